// Round 1
// baseline (90.978 us; speedup 1.0000x reference)
//
#include <hip/hip_runtime.h>
#include <math.h>

#define NSAMP 524288      // 2^19 samples per channel
#define CHUNK 128         // samples per block-thread
#define NBLK (NSAMP / CHUNK)   // 4096 blocks per channel
#define HIDDEN 16
#define SCAN_T 256        // threads in scan kernel
#define GRP (NBLK / SCAN_T)    // 16 blocks composed serially per scan thread

__device__ __forceinline__ float fast_tanh(float x) {
    float e = __expf(2.0f * x);
    return (e - 1.0f) / (e + 1.0f);
}

// ---------------- Kernel P: per-sample all-pass coefficient ----------------
__global__ void k_compute_p(const float* __restrict__ rate01,
                            const float* __restrict__ phoff01,
                            const float* __restrict__ W1,
                            const float* __restrict__ b1,
                            const float* __restrict__ W2,
                            const float* __restrict__ b2,
                            const float* __restrict__ amp,
                            const float* __restrict__ bias_,
                            const float* __restrict__ depth_,
                            const float* __restrict__ prevph,
                            float* __restrict__ P) {
    int gid = blockIdx.x * blockDim.x + threadIdx.x;   // 0 .. 2*NSAMP-1
    int c = gid >> 19;
    int i = gid & (NSAMP - 1);
    const float two_pi = 6.28318530717958647692f;
    float rate = rate01[0] * 4.9f + 0.1f;
    float w0 = two_pi * rate / 44100.0f;
    float arg = w0 * (float)(i + 1) + prevph[0];
    if (c == 1) arg += phoff01[0] * two_pi;
    float lfo = amp[0] * cosf(arg);
    float m = b2[0];
#pragma unroll
    for (int j = 0; j < HIDDEN; ++j) {
        float h = fast_tanh(fmaf(lfo, W1[j], b1[j]));
        m = fmaf(h, W2[j], m);
    }
    float d = fmaf(depth_[0] * 0.5f, 1.0f + m, bias_[0]);
    float td = tanf(d);
    float pv = fast_tanh((1.0f - td) / (1.0f + td));
    P[gid] = pv;
}

// ------------- Kernel T: per-block affine transform (M 5x5, d 5) -------------
// state s = [u0, y0, y1, y2, y3]; per sample:
//   u0' = xin + g1*y3;  y0' = p*(u0'-y0)+u0;  yk' = p*(y_{k-1}'-yk)+y_{k-1}
__global__ void k_block_transforms(const float* __restrict__ X,
                                   const float* __restrict__ P,
                                   const float* __restrict__ g1p,
                                   float* __restrict__ T) {
    int tid = blockIdx.x * blockDim.x + threadIdx.x;  // 0 .. 2*NBLK-1
    int c = tid >> 12;          // NBLK = 4096 = 2^12
    int b = tid & (NBLK - 1);
    const float g1 = g1p[0];
    long base = (long)c * NSAMP + (long)b * CHUNK;

    float v[6][5];   // 5 basis vectors + 1 zero-init input vector
#pragma unroll
    for (int j = 0; j < 6; ++j)
#pragma unroll
        for (int r = 0; r < 5; ++r)
            v[j][r] = (j == r) ? 1.0f : 0.0f;   // j==5 row -> all zeros

    for (int i = 0; i < CHUNK; ++i) {
        float pp = P[base + i];
        float xx = X[base + i];
#pragma unroll
        for (int j = 0; j < 6; ++j) {
            float xin = (j == 5) ? xx : 0.0f;
            float u0 = fmaf(g1, v[j][4], xin);
            float y0 = fmaf(pp, u0 - v[j][1], v[j][0]);
            float y1 = fmaf(pp, y0 - v[j][2], v[j][1]);
            float y2 = fmaf(pp, y1 - v[j][3], v[j][2]);
            float y3 = fmaf(pp, y2 - v[j][4], v[j][3]);
            v[j][0] = u0; v[j][1] = y0; v[j][2] = y1; v[j][3] = y2; v[j][4] = y3;
        }
    }
    // layout: 25 floats M row-major (M[r][col]), 5 floats d; stride 32
    float* o = T + (long)tid * 32;
#pragma unroll
    for (int j = 0; j < 5; ++j)
#pragma unroll
        for (int r = 0; r < 5; ++r)
            o[r * 5 + j] = v[j][r];   // column j of M = final basis vector j
#pragma unroll
    for (int r = 0; r < 5; ++r) o[25 + r] = v[5][r];
}

// ------------- Kernel S: scan over block transforms, emit init states -------
__global__ void k_scan(const float* __restrict__ T,
                       float* __restrict__ IS) {
    int c = blockIdx.x;          // channel
    int t = threadIdx.x;         // 0..255
    __shared__ float sM[SCAN_T][30];

    // serially compose GRP consecutive block transforms
    const float* Tb = T + ((long)c * NBLK + (long)t * GRP) * 32;
    float M[25], d[5];
#pragma unroll
    for (int k = 0; k < 25; ++k) M[k] = Tb[k];
#pragma unroll
    for (int r = 0; r < 5; ++r) d[r] = Tb[25 + r];
    for (int g = 1; g < GRP; ++g) {
        const float* Tg = Tb + (long)g * 32;
        float Mg[25], dg[5];
#pragma unroll
        for (int k = 0; k < 25; ++k) Mg[k] = Tg[k];
#pragma unroll
        for (int r = 0; r < 5; ++r) dg[r] = Tg[25 + r];
        float Mn[25], dn[5];
#pragma unroll
        for (int r = 0; r < 5; ++r) {
#pragma unroll
            for (int c2 = 0; c2 < 5; ++c2) {
                float acc = 0.0f;
#pragma unroll
                for (int k = 0; k < 5; ++k) acc = fmaf(Mg[r*5+k], M[k*5+c2], acc);
                Mn[r*5+c2] = acc;
            }
            float accd = dg[r];
#pragma unroll
            for (int k = 0; k < 5; ++k) accd = fmaf(Mg[r*5+k], d[k], accd);
            dn[r] = accd;
        }
#pragma unroll
        for (int k = 0; k < 25; ++k) M[k] = Mn[k];
#pragma unroll
        for (int r = 0; r < 5; ++r) d[r] = dn[r];
    }

#pragma unroll
    for (int k = 0; k < 25; ++k) sM[t][k] = M[k];
#pragma unroll
    for (int r = 0; r < 5; ++r) sM[t][25 + r] = d[r];
    __syncthreads();

    // Hillis-Steele inclusive scan (cur = cur ∘ prev)
    for (int off = 1; off < SCAN_T; off <<= 1) {
        float pM[25], pd[5];
        bool act = (t >= off);
        if (act) {
#pragma unroll
            for (int k = 0; k < 25; ++k) pM[k] = sM[t - off][k];
#pragma unroll
            for (int r = 0; r < 5; ++r) pd[r] = sM[t - off][25 + r];
        }
        __syncthreads();
        if (act) {
            float Mn[25], dn[5];
#pragma unroll
            for (int r = 0; r < 5; ++r) {
#pragma unroll
                for (int c2 = 0; c2 < 5; ++c2) {
                    float acc = 0.0f;
#pragma unroll
                    for (int k = 0; k < 5; ++k) acc = fmaf(M[r*5+k], pM[k*5+c2], acc);
                    Mn[r*5+c2] = acc;
                }
                float accd = d[r];
#pragma unroll
                for (int k = 0; k < 5; ++k) accd = fmaf(M[r*5+k], pd[k], accd);
                dn[r] = accd;
            }
#pragma unroll
            for (int k = 0; k < 25; ++k) { M[k] = Mn[k]; sM[t][k] = Mn[k]; }
#pragma unroll
            for (int r = 0; r < 5; ++r) { d[r] = dn[r]; sM[t][25 + r] = dn[r]; }
        }
        __syncthreads();
    }

    // exclusive prefix applied to zero initial state -> just the d-part
    float s[5];
    if (t == 0) {
#pragma unroll
        for (int r = 0; r < 5; ++r) s[r] = 0.0f;
    } else {
#pragma unroll
        for (int r = 0; r < 5; ++r) s[r] = sM[t - 1][25 + r];
    }

    // back-substitute within the group, storing each block's incoming state
    for (int g = 0; g < GRP; ++g) {
        long b = (long)c * NBLK + (long)t * GRP + g;
        float* isp = IS + b * 8;
#pragma unroll
        for (int r = 0; r < 5; ++r) isp[r] = s[r];
        const float* Tg = T + b * 32;
        float sn[5];
#pragma unroll
        for (int r = 0; r < 5; ++r) {
            float acc = Tg[25 + r];
#pragma unroll
            for (int k = 0; k < 5; ++k) acc = fmaf(Tg[r*5+k], s[k], acc);
            sn[r] = acc;
        }
#pragma unroll
        for (int r = 0; r < 5; ++r) s[r] = sn[r];
    }
}

// ------------- Kernel E: recompute blocks with correct init, emit output ----
__global__ void k_emit(const float* __restrict__ X,
                       const float* __restrict__ P,
                       const float* __restrict__ IS,
                       const float* __restrict__ g1p,
                       float* __restrict__ OUT) {
    int tid = blockIdx.x * blockDim.x + threadIdx.x;
    int c = tid >> 12;
    int b = tid & (NBLK - 1);
    const float g1 = g1p[0];
    long base = (long)c * NSAMP + (long)b * CHUNK;
    const float* isp = IS + (long)tid * 8;
    float s0 = isp[0], s1 = isp[1], s2 = isp[2], s3 = isp[3], s4 = isp[4];
    for (int i = 0; i < CHUNK; ++i) {
        float pp = P[base + i];
        float xx = X[base + i];
        float u0 = fmaf(g1, s4, xx);
        float y0 = fmaf(pp, u0 - s1, s0);
        float y1 = fmaf(pp, y0 - s2, s1);
        float y2 = fmaf(pp, y1 - s3, s2);
        float y3 = fmaf(pp, y2 - s4, s3);
        s0 = u0; s1 = y0; s2 = y1; s3 = y2; s4 = y3;
        OUT[base + i] = 0.5f * (xx + y3);
    }
}

extern "C" void kernel_launch(void* const* d_in, const int* in_sizes, int n_in,
                              void* d_out, int out_size, void* d_ws, size_t ws_size,
                              hipStream_t stream) {
    const float* x     = (const float*)d_in[0];
    const float* rate  = (const float*)d_in[1];
    const float* phoff = (const float*)d_in[2];
    const float* W1    = (const float*)d_in[3];
    const float* b1    = (const float*)d_in[4];
    const float* W2    = (const float*)d_in[5];
    const float* b2    = (const float*)d_in[6];
    const float* amp   = (const float*)d_in[7];
    const float* bias_ = (const float*)d_in[8];
    const float* depth = (const float*)d_in[9];
    const float* g1    = (const float*)d_in[10];
    const float* pph   = (const float*)d_in[11];
    float* out = (float*)d_out;

    float* P  = (float*)d_ws;              // 2*NSAMP floats      (4 MB)
    float* T  = P + 2 * NSAMP;             // 2*NBLK*32 floats    (1 MB)
    float* IS = T + 2 * NBLK * 32;         // 2*NBLK*8 floats     (256 KB)

    k_compute_p<<<(2 * NSAMP) / 256, 256, 0, stream>>>(
        rate, phoff, W1, b1, W2, b2, amp, bias_, depth, pph, P);
    k_block_transforms<<<(2 * NBLK) / 64, 64, 0, stream>>>(x, P, g1, T);
    k_scan<<<2, SCAN_T, 0, stream>>>(T, IS);
    k_emit<<<(2 * NBLK) / 64, 64, 0, stream>>>(x, P, IS, g1, out);
}

// Round 2
// 39.934 us; speedup vs baseline: 2.2782x; 2.2782x over previous
//
#include <hip/hip_runtime.h>
#include <math.h>

#define NSAMP 524288              // 2^19 samples per channel
#define CHUNK 32                  // samples per block-thread
#define NBLK (NSAMP / CHUNK)      // 16384 blocks per channel
#define WGT 128                   // threads per scan workgroup
#define NWG (NBLK / WGT)          // 128 workgroups per channel
#define HIDDEN 16
#define LS 33                     // LDS row stride (33 floats, conflict-free)

__device__ __forceinline__ float fast_tanh(float x) {
    float e = __expf(2.0f * x);
    return (e - 1.0f) / (e + 1.0f);
}

// (Mo,do) = (Ma,da) ∘ (Mb,db): apply b first, then a
__device__ __forceinline__ void compose5(const float* Ma, const float* da,
                                         const float* Mb, const float* db,
                                         float* Mo, float* dout) {
#pragma unroll
    for (int r = 0; r < 5; ++r) {
#pragma unroll
        for (int c = 0; c < 5; ++c) {
            float acc = 0.0f;
#pragma unroll
            for (int k = 0; k < 5; ++k) acc = fmaf(Ma[r*5+k], Mb[k*5+c], acc);
            Mo[r*5+c] = acc;
        }
        float acc = da[r];
#pragma unroll
        for (int k = 0; k < 5; ++k) acc = fmaf(Ma[r*5+k], db[k], acc);
        dout[r] = acc;
    }
}

// ---------------- K1: per-sample all-pass coefficient (4/thread) ----------
__global__ void k_compute_p(const float* __restrict__ rate01,
                            const float* __restrict__ phoff01,
                            const float* __restrict__ W1,
                            const float* __restrict__ b1,
                            const float* __restrict__ W2,
                            const float* __restrict__ b2,
                            const float* __restrict__ amp,
                            const float* __restrict__ bias_,
                            const float* __restrict__ depth_,
                            const float* __restrict__ prevph,
                            float* __restrict__ P) {
    int gid = blockIdx.x * blockDim.x + threadIdx.x;   // 0 .. 2*NSAMP/4-1
    int c = gid >> 17;                                 // (gid*4) >> 19
    int i0 = (gid << 2) & (NSAMP - 1);
    const float two_pi = 6.28318530717958647692f;
    float rate = fmaf(rate01[0], 4.9f, 0.1f);
    float w0 = two_pi * rate / 44100.0f;
    float ab = prevph[0] + (c ? phoff01[0] * two_pi : 0.0f);
    float dscale = depth_[0] * 0.5f;
    float res[4];
#pragma unroll
    for (int k = 0; k < 4; ++k) {
        float arg = fmaf(w0, (float)(i0 + k + 1), ab);
        float lfo = amp[0] * cosf(arg);
        float m = b2[0];
#pragma unroll
        for (int j = 0; j < HIDDEN; ++j) {
            float h = fast_tanh(fmaf(lfo, W1[j], b1[j]));
            m = fmaf(h, W2[j], m);
        }
        float d = fmaf(dscale, 1.0f + m, bias_[0]);
        float td = __tanf(d);
        res[k] = fast_tanh((1.0f - td) / (1.0f + td));
    }
    float4 o; o.x = res[0]; o.y = res[1]; o.z = res[2]; o.w = res[3];
    ((float4*)P)[gid] = o;
}

// ------- K2: block transforms + intra-workgroup inclusive scan ------------
// state s = [u0, y0, y1, y2, y3]
__global__ void __launch_bounds__(WGT) k_tscan(const float* __restrict__ X,
                                               const float* __restrict__ P,
                                               const float* __restrict__ g1p,
                                               float* __restrict__ REC) {
    __shared__ float sM[WGT * LS];
    int wg = blockIdx.x;                 // 0 .. 2*NWG-1
    int c = wg >> 7;                     // NWG = 128
    int wc = wg & (NWG - 1);
    int t = threadIdx.x;
    int b = wc * WGT + t;                // block index within channel
    long base = (long)c * NSAMP + (long)b * CHUNK;
    const float4* Pv = (const float4*)(P + base);
    const float4* Xv = (const float4*)(X + base);
    const float g1 = g1p[0];

    float v[6][5];                       // 5 basis vectors + zero-init input vec
#pragma unroll
    for (int j = 0; j < 6; ++j)
#pragma unroll
        for (int r = 0; r < 5; ++r) v[j][r] = (j == r) ? 1.0f : 0.0f;

#pragma unroll
    for (int q = 0; q < CHUNK / 4; ++q) {
        float4 p4 = Pv[q], x4 = Xv[q];
        float pa[4] = {p4.x, p4.y, p4.z, p4.w};
        float xa[4] = {x4.x, x4.y, x4.z, x4.w};
#pragma unroll
        for (int ii = 0; ii < 4; ++ii) {
            float pp = pa[ii], xx = xa[ii];
#pragma unroll
            for (int j = 0; j < 6; ++j) {
                float xin = (j == 5) ? xx : 0.0f;
                float u0 = fmaf(g1, v[j][4], xin);
                float y0 = fmaf(pp, u0 - v[j][1], v[j][0]);
                float y1 = fmaf(pp, y0 - v[j][2], v[j][1]);
                float y2 = fmaf(pp, y1 - v[j][3], v[j][2]);
                float y3 = fmaf(pp, y2 - v[j][4], v[j][3]);
                v[j][0] = u0; v[j][1] = y0; v[j][2] = y1; v[j][3] = y2; v[j][4] = y3;
            }
        }
    }

    float M[25], d[5];
#pragma unroll
    for (int j = 0; j < 5; ++j)
#pragma unroll
        for (int r = 0; r < 5; ++r) M[r*5+j] = v[j][r];
#pragma unroll
    for (int r = 0; r < 5; ++r) d[r] = v[5][r];

#pragma unroll
    for (int k = 0; k < 25; ++k) sM[t*LS + k] = M[k];
#pragma unroll
    for (int r = 0; r < 5; ++r) sM[t*LS + 25 + r] = d[r];
    __syncthreads();

    for (int off = 1; off < WGT; off <<= 1) {
        float pM[25], pd[5];
        bool act = (t >= off);
        if (act) {
#pragma unroll
            for (int k = 0; k < 25; ++k) pM[k] = sM[(t-off)*LS + k];
#pragma unroll
            for (int r = 0; r < 5; ++r) pd[r] = sM[(t-off)*LS + 25 + r];
        }
        __syncthreads();
        if (act) {
            float Mn[25], dn[5];
            compose5(M, d, pM, pd, Mn, dn);
#pragma unroll
            for (int k = 0; k < 25; ++k) { M[k] = Mn[k]; sM[t*LS + k] = Mn[k]; }
#pragma unroll
            for (int r = 0; r < 5; ++r) { d[r] = dn[r]; sM[t*LS + 25 + r] = dn[r]; }
        }
        __syncthreads();
    }

    // write inclusive-prefix record (32 floats, float4-vectorized)
    float out[32];
#pragma unroll
    for (int k = 0; k < 25; ++k) out[k] = M[k];
#pragma unroll
    for (int r = 0; r < 5; ++r) out[25 + r] = d[r];
    out[30] = 0.0f; out[31] = 0.0f;
    float4* rv = (float4*)(REC + ((long)(c * NBLK + b)) * 32);
#pragma unroll
    for (int q = 0; q < 8; ++q) {
        float4 o; o.x = out[q*4]; o.y = out[q*4+1]; o.z = out[q*4+2]; o.w = out[q*4+3];
        rv[q] = o;
    }
}

// ------- K3: scan the per-workgroup aggregates -> workgroup entry states ---
__global__ void __launch_bounds__(NWG) k_midscan(const float* __restrict__ REC,
                                                 float* __restrict__ WGS) {
    __shared__ float sM[NWG * LS];
    int c = blockIdx.x;
    int t = threadIdx.x;                 // 0..NWG-1
    const float4* rv = (const float4*)(REC +
        ((long)(c * NBLK + t * WGT + (WGT - 1))) * 32);
    float r[32];
#pragma unroll
    for (int q = 0; q < 8; ++q) {
        float4 f = rv[q];
        r[q*4] = f.x; r[q*4+1] = f.y; r[q*4+2] = f.z; r[q*4+3] = f.w;
    }
    float M[25], d[5];
#pragma unroll
    for (int k = 0; k < 25; ++k) M[k] = r[k];
#pragma unroll
    for (int k = 0; k < 5; ++k) d[k] = r[25 + k];

#pragma unroll
    for (int k = 0; k < 25; ++k) sM[t*LS + k] = M[k];
#pragma unroll
    for (int k = 0; k < 5; ++k) sM[t*LS + 25 + k] = d[k];
    __syncthreads();

    for (int off = 1; off < NWG; off <<= 1) {
        float pM[25], pd[5];
        bool act = (t >= off);
        if (act) {
#pragma unroll
            for (int k = 0; k < 25; ++k) pM[k] = sM[(t-off)*LS + k];
#pragma unroll
            for (int k = 0; k < 5; ++k) pd[k] = sM[(t-off)*LS + 25 + k];
        }
        __syncthreads();
        if (act) {
            float Mn[25], dn[5];
            compose5(M, d, pM, pd, Mn, dn);
#pragma unroll
            for (int k = 0; k < 25; ++k) { M[k] = Mn[k]; sM[t*LS + k] = Mn[k]; }
#pragma unroll
            for (int k = 0; k < 5; ++k) { d[k] = dn[k]; sM[t*LS + 25 + k] = dn[k]; }
        }
        __syncthreads();
    }

    // exclusive: state entering workgroup t (zero initial state -> d-part)
#pragma unroll
    for (int k = 0; k < 5; ++k) {
        float s = (t == 0) ? 0.0f : sM[(t-1)*LS + 25 + k];
        WGS[(c * NWG + t) * 8 + k] = s;
    }
}

// ------- K4: apply exclusive prefix, run recursion, emit output ------------
__global__ void __launch_bounds__(WGT) k_emit(const float* __restrict__ X,
                                              const float* __restrict__ P,
                                              const float* __restrict__ REC,
                                              const float* __restrict__ WGS,
                                              const float* __restrict__ g1p,
                                              float* __restrict__ OUT) {
    int wg = blockIdx.x;
    int c = wg >> 7;
    int wc = wg & (NWG - 1);
    int t = threadIdx.x;
    int b = wc * WGT + t;
    const float g1 = g1p[0];

    float sw[5];
#pragma unroll
    for (int k = 0; k < 5; ++k) sw[k] = WGS[(c * NWG + wc) * 8 + k];

    float s[5];
    if (t == 0) {
#pragma unroll
        for (int k = 0; k < 5; ++k) s[k] = sw[k];
    } else {
        const float4* rv = (const float4*)(REC + ((long)(c * NBLK + b - 1)) * 32);
        float r[32];
#pragma unroll
        for (int q = 0; q < 8; ++q) {
            float4 f = rv[q];
            r[q*4] = f.x; r[q*4+1] = f.y; r[q*4+2] = f.z; r[q*4+3] = f.w;
        }
#pragma unroll
        for (int k = 0; k < 5; ++k) {
            float acc = r[25 + k];
#pragma unroll
            for (int j = 0; j < 5; ++j) acc = fmaf(r[k*5+j], sw[j], acc);
            s[k] = acc;
        }
    }

    long base = (long)c * NSAMP + (long)b * CHUNK;
    const float4* Pv = (const float4*)(P + base);
    const float4* Xv = (const float4*)(X + base);
    float4* Ov = (float4*)(OUT + base);
    float s0 = s[0], s1 = s[1], s2 = s[2], s3 = s[3], s4 = s[4];
#pragma unroll
    for (int q = 0; q < CHUNK / 4; ++q) {
        float4 p4 = Pv[q], x4 = Xv[q];
        float pa[4] = {p4.x, p4.y, p4.z, p4.w};
        float xa[4] = {x4.x, x4.y, x4.z, x4.w};
        float oa[4];
#pragma unroll
        for (int ii = 0; ii < 4; ++ii) {
            float pp = pa[ii], xx = xa[ii];
            float u0 = fmaf(g1, s4, xx);
            float y0 = fmaf(pp, u0 - s1, s0);
            float y1 = fmaf(pp, y0 - s2, s1);
            float y2 = fmaf(pp, y1 - s3, s2);
            float y3 = fmaf(pp, y2 - s4, s3);
            s0 = u0; s1 = y0; s2 = y1; s3 = y2; s4 = y3;
            oa[ii] = 0.5f * (xx + y3);
        }
        float4 o; o.x = oa[0]; o.y = oa[1]; o.z = oa[2]; o.w = oa[3];
        Ov[q] = o;
    }
}

extern "C" void kernel_launch(void* const* d_in, const int* in_sizes, int n_in,
                              void* d_out, int out_size, void* d_ws, size_t ws_size,
                              hipStream_t stream) {
    const float* x     = (const float*)d_in[0];
    const float* rate  = (const float*)d_in[1];
    const float* phoff = (const float*)d_in[2];
    const float* W1    = (const float*)d_in[3];
    const float* b1    = (const float*)d_in[4];
    const float* W2    = (const float*)d_in[5];
    const float* b2    = (const float*)d_in[6];
    const float* amp   = (const float*)d_in[7];
    const float* bias_ = (const float*)d_in[8];
    const float* depth = (const float*)d_in[9];
    const float* g1    = (const float*)d_in[10];
    const float* pph   = (const float*)d_in[11];
    float* out = (float*)d_out;

    float* P   = (float*)d_ws;                 // 2*NSAMP floats        (4 MB)
    float* REC = P + 2 * NSAMP;                // 2*NBLK*32 floats      (4 MB)
    float* WGS = REC + 2L * NBLK * 32;         // 2*NWG*8 floats        (8 KB)

    k_compute_p<<<(2 * NSAMP / 4) / 256, 256, 0, stream>>>(
        rate, phoff, W1, b1, W2, b2, amp, bias_, depth, pph, P);
    k_tscan<<<2 * NWG, WGT, 0, stream>>>(x, P, g1, REC);
    k_midscan<<<2, NWG, 0, stream>>>(REC, WGS);
    k_emit<<<2 * NWG, WGT, 0, stream>>>(x, P, REC, WGS, g1, out);
}